// Round 2
// baseline (83.419 us; speedup 1.0000x reference)
//
#include <hip/hip_runtime.h>

#define L_RES 4096
#define EPSF 1e-8f

struct V3 { float x, y, z; };

__device__ __forceinline__ V3 v3sub(V3 a, V3 b) { return {a.x-b.x, a.y-b.y, a.z-b.z}; }
__device__ __forceinline__ V3 v3cross(V3 a, V3 b) {
    return {a.y*b.z - a.z*b.y, a.z*b.x - a.x*b.z, a.x*b.y - a.y*b.x};
}
__device__ __forceinline__ float v3dot(V3 a, V3 b) { return a.x*b.x + a.y*b.y + a.z*b.z; }

// sin/cos of the reference dihedral:
//   angle = arccos(clip(dot(n1n,n2n))); dihedral = angle * sign(dot(n1n, v3))
//   sign != 0: sin = sign*sqrt(1-c^2), cos = c.  sign == 0: dihedral=0 -> sin=0, cos=1.
__device__ __forceinline__ void dihedral_sc(V3 p1, V3 p2, V3 p3, V3 p4,
                                            float& s_out, float& c_out) {
    V3 v1 = v3sub(p2, p1);
    V3 v2 = v3sub(p3, p2);
    V3 v3 = v3sub(p4, p3);
    V3 n1 = v3cross(v1, v2);
    V3 n2 = v3cross(v2, v3);
    float sq1 = v3dot(n1, n1);
    float sq2 = v3dot(n2, n2);
    float nrm1 = (sq1 > 0.f) ? sqrtf(sq1) : 0.f;   // _safe_norm semantics
    float nrm2 = (sq2 > 0.f) ? sqrtf(sq2) : 0.f;
    float inv1 = 1.f / (nrm1 + EPSF);
    float inv2 = 1.f / (nrm2 + EPSF);
    float c = v3dot(n1, n2) * (inv1 * inv2);
    c = fminf(1.f, fmaxf(-1.f, c));
    float sg = v3dot(n1, v3) * inv1;               // same sign as dot(n1n, v3)
    float sgn = (sg > 0.f) ? 1.f : ((sg < 0.f) ? -1.f : 0.f);
    float s = sqrtf(fmaxf(0.f, (1.f - c) * (1.f + c)));
    s_out = sgn * s;
    c_out = (sg == 0.f) ? 1.f : c;
}

// Block = 256 threads; block handles 256 consecutive residues of one batch row.
// Phase 1: thread t computes 6 encodings for its residue -> LDS (8-float padded rows).
// Phase 2: thread t owns dims [4*(t&15), +4); loops 16 residues; fully coalesced
//          float4 stores; LDS reads are b128+b64 16-lane broadcasts (conflict-free).
__global__ __launch_bounds__(256) void dihedral_enc_kernel(
        const float* __restrict__ coords,   // (B, L, 4, 3)
        const float* __restrict__ W,        // (64, 6) row-major
        const float* __restrict__ bias,     // (64,)
        float* __restrict__ out) {          // (B, L, 64)
    __shared__ float enc_s[256 * 8];

    const int t   = threadIdx.x;
    const int blk = blockIdx.x;
    const int b   = blk >> 4;
    const int l   = ((blk & 15) << 8) + t;

    const float4* c4 = (const float4*)coords;
    const long base  = ((long)b * L_RES + l) * 3;        // float4 index of own residue
    const long pbase = base - ((l != 0) ? 3 : 0);
    const bool is_last = (l == L_RES - 1);
    const long nbase = base + (is_last ? 0 : 3);

    // own residue: 12 floats = N, CA, C, O(unused)
    float4 a0 = c4[base + 0];
    float4 a1 = c4[base + 1];
    float4 a2 = c4[base + 2];
    // prev residue: need C = floats 6,7,8
    float4 p1 = c4[pbase + 1];
    float4 p2 = c4[pbase + 2];
    // next residue: need N = floats 0..2, CA = floats 3..5
    float4 q0 = c4[nbase + 0];
    float4 q1 = c4[nbase + 1];

    // W rows for this thread's 4 dims: 24 contiguous floats = 6 float4 loads
    const int dg = t & 15;          // dim group: dims 4*dg .. 4*dg+3
    float wf[24];
    {
        const float4* w4 = (const float4*)W;
        #pragma unroll
        for (int i = 0; i < 6; ++i) {
            float4 v = w4[6 * dg + i];
            wf[4*i+0] = v.x; wf[4*i+1] = v.y; wf[4*i+2] = v.z; wf[4*i+3] = v.w;
        }
    }
    const float4 bcol = *(const float4*)&bias[dg << 2];

    V3 N  = {a0.x, a0.y, a0.z};
    V3 CA = {a0.w, a1.x, a1.y};
    V3 C  = {a1.z, a1.w, a2.x};
    V3 C_prev  = {p1.z, p1.w, p2.x};
    V3 N_next  = {q0.x, q0.y, q0.z};
    V3 CA_next = {q0.w, q1.x, q1.y};
    V3 om3 = is_last ? CA : N_next;
    V3 om4 = is_last ? CA : CA_next;

    float s_phi, c_phi, s_psi, c_psi, s_om, c_om;
    dihedral_sc(C_prev, N, CA, C,  s_phi, c_phi);
    dihedral_sc(N, CA, C, N_next,  s_psi, c_psi);
    dihedral_sc(CA, C, om3, om4,   s_om,  c_om);

    *(float4*)&enc_s[t * 8]     = make_float4(s_phi, s_psi, s_om, c_phi);
    *(float2*)&enc_s[t * 8 + 4] = make_float2(c_psi, c_om);

    __syncthreads();

    // wcol[k][j] = W[4*dg+j][k]; row j lives at wf[6j..6j+5]
    float4 wc0 = make_float4(wf[0], wf[6],  wf[12], wf[18]);
    float4 wc1 = make_float4(wf[1], wf[7],  wf[13], wf[19]);
    float4 wc2 = make_float4(wf[2], wf[8],  wf[14], wf[20]);
    float4 wc3 = make_float4(wf[3], wf[9],  wf[15], wf[21]);
    float4 wc4 = make_float4(wf[4], wf[10], wf[16], wf[22]);
    float4 wc5 = make_float4(wf[5], wf[11], wf[17], wf[23]);

    const int rg = t >> 4;                  // residue subgroup 0..15
    float4* outp = (float4*)out;
    const long ob4 = (long)blk * 4096;      // blk * 256 residues * 64 dims / 4

    #pragma unroll 8
    for (int it = 0; it < 16; ++it) {
        const int r = it * 16 + rg;
        float4 e03 = *(const float4*)&enc_s[r * 8];      // broadcast b128
        float2 e45 = *(const float2*)&enc_s[r * 8 + 4];  // broadcast b64
        float4 o;
        o.x = fmaf(e03.x, wc0.x, fmaf(e03.y, wc1.x, fmaf(e03.z, wc2.x,
              fmaf(e03.w, wc3.x, fmaf(e45.x, wc4.x, fmaf(e45.y, wc5.x, bcol.x))))));
        o.y = fmaf(e03.x, wc0.y, fmaf(e03.y, wc1.y, fmaf(e03.z, wc2.y,
              fmaf(e03.w, wc3.y, fmaf(e45.x, wc4.y, fmaf(e45.y, wc5.y, bcol.y))))));
        o.z = fmaf(e03.x, wc0.z, fmaf(e03.y, wc1.z, fmaf(e03.z, wc2.z,
              fmaf(e03.w, wc3.z, fmaf(e45.x, wc4.z, fmaf(e45.y, wc5.z, bcol.z))))));
        o.w = fmaf(e03.x, wc0.w, fmaf(e03.y, wc1.w, fmaf(e03.z, wc2.w,
              fmaf(e03.w, wc3.w, fmaf(e45.x, wc4.w, fmaf(e45.y, wc5.w, bcol.w))))));
        outp[ob4 + it * 256 + t] = o;
    }
}

extern "C" void kernel_launch(void* const* d_in, const int* in_sizes, int n_in,
                              void* d_out, int out_size, void* d_ws, size_t ws_size,
                              hipStream_t stream) {
    const float* coords = (const float*)d_in[0];
    const float* W      = (const float*)d_in[1];
    const float* bias   = (const float*)d_in[2];
    float* out          = (float*)d_out;

    const int total_res = in_sizes[0] / 12;      // B * L
    const int blocks    = total_res / 256;       // 1024 for B=64, L=4096
    dihedral_enc_kernel<<<blocks, 256, 0, stream>>>(coords, W, bias, out);
}